// Round 7
// baseline (182.993 us; speedup 1.0000x reference)
//
#include <hip/hip_runtime.h>
#include <hip/hip_bf16.h>

#define HEADS 8
#define DHEAD 64
#define CDIM  512
#define SEQ   2304      // 48*48
#define ND    512       // HEADS*DHEAD
#define NCHUNK 4        // split-K chunks over the 36 key-tiles (9 tiles each)

typedef unsigned short u16;
typedef unsigned int   u32;
typedef __attribute__((ext_vector_type(8))) short short8;
typedef __attribute__((ext_vector_type(4))) float f32x4;

#define QSCALE 0.18033688011112043f   // 0.125 * log2(e): folded into Q so softmax is exp2

__device__ __forceinline__ u16 f2bf(float f) {
    union { float f; u32 u; } x; x.f = f;
    u32 r = x.u + 0x7FFFu + ((x.u >> 16) & 1u);   // RNE
    return (u16)(r >> 16);
}
__device__ __forceinline__ float bf2f(u16 v) {
    union { u32 u; float f; } x; x.u = ((u32)v) << 16; return x.f;
}
// pack two f32 -> two bf16 in one u32 (round-half-up via +0x8000, then v_perm byte-select)
__device__ __forceinline__ u32 pkbf(float a, float b) {
    union { float f; u32 u; } x, y; x.f = a; y.f = b;
    return __builtin_amdgcn_perm(y.u + 0x8000u, x.u + 0x8000u, 0x07060302u);
}
// single-instruction packed f32->bf16 (RNE); lo result = first operand
__device__ __forceinline__ u32 cvtpk(float lo, float hi) {
    u32 r;
    asm("v_cvt_pk_bf16_f32 %0, %1, %2" : "=v"(r) : "v"(lo), "v"(hi));
    return r;
}
__device__ __forceinline__ f32x4 mfma16(short8 a, short8 b, f32x4 c) {
    return __builtin_amdgcn_mfma_f32_16x16x32_bf16(a, b, c, 0, 0, 0);
}
// async 16B global->LDS (wave-uniform base + lane*16 dest)
__device__ __forceinline__ void cp16(const void* g, void* l) {
    __builtin_amdgcn_global_load_lds(
        (const __attribute__((address_space(1))) u32*)(uintptr_t)g,
        (__attribute__((address_space(3))) u32*)(u32)(uintptr_t)l,
        16, 0, 0);
}
// LDS K-slot r holds source K row kperm_inv(r), so post-softmax P sits in PV B-frag order.
__device__ __forceinline__ int kperm_inv(int r) {
    return (r & ~0x1C) | ((r & 0x0C) << 1) | ((r & 0x10) >> 2);
}

// ---------------- fused: weight convert (uint4-vectorized) + x transpose (64x64 tiles)
__global__ void prep_kernel(const float* __restrict__ H,
                            const float* __restrict__ Wq, const float* __restrict__ Wk,
                            const float* __restrict__ Wv, const float* __restrict__ Wo,
                            u16* __restrict__ Wqkv, u16* __restrict__ Wob,
                            u16* __restrict__ X) {
    __shared__ float tile[64][65];
    const int t = threadIdx.x;
    const int bx = blockIdx.x;
    if (bx < 512) {
        const int N1 = CDIM * ND;                 // 262144 (divisible by 8)
        int i8 = (bx * 256 + t) * 8;
        const float* src;
        u16* dst;
        if (i8 < 3 * N1) {
            src = (i8 < N1) ? &Wq[i8] : (i8 < 2 * N1 ? &Wk[i8 - N1] : &Wv[i8 - 2 * N1]);
            dst = &Wqkv[i8];
        } else {
            src = &Wo[i8 - 3 * N1];
            dst = &Wob[i8 - 3 * N1];
        }
        float4 a = *(const float4*)src;
        float4 c = *(const float4*)(src + 4);
        uint4 o;
        o.x = pkbf(a.x, a.y); o.y = pkbf(a.z, a.w);
        o.z = pkbf(c.x, c.y); o.w = pkbf(c.z, c.w);
        *(uint4*)dst = o;
    } else {
        int bb = bx - 512;                        // 0..575
        int st = bb % 36, ct = (bb / 36) % 8, b = bb / (36 * 8);
        // load: 64 c-rows x 64 s, float4/thread x4 (coalesced along s)
#pragma unroll
        for (int it = 0; it < 4; ++it) {
            int cl = it * 16 + (t >> 4);
            int j4 = (t & 15) * 4;
            float4 hv = *(const float4*)&H[((size_t)(b * CDIM + ct * 64 + cl)) * SEQ + st * 64 + j4];
            tile[cl][j4 + 0] = hv.x; tile[cl][j4 + 1] = hv.y;
            tile[cl][j4 + 2] = hv.z; tile[cl][j4 + 3] = hv.w;
        }
        __syncthreads();
        // store: 64 s-rows, 16 consecutive c per thread as two uint4 (16 bf16 = 32B)
        int sl = t >> 2, c16 = (t & 3) * 16;
        uint4 o1, o2;
        o1.x = cvtpk(tile[c16 +  0][sl], tile[c16 +  1][sl]);
        o1.y = cvtpk(tile[c16 +  2][sl], tile[c16 +  3][sl]);
        o1.z = cvtpk(tile[c16 +  4][sl], tile[c16 +  5][sl]);
        o1.w = cvtpk(tile[c16 +  6][sl], tile[c16 +  7][sl]);
        o2.x = cvtpk(tile[c16 +  8][sl], tile[c16 +  9][sl]);
        o2.y = cvtpk(tile[c16 + 10][sl], tile[c16 + 11][sl]);
        o2.z = cvtpk(tile[c16 + 12][sl], tile[c16 + 13][sl]);
        o2.w = cvtpk(tile[c16 + 14][sl], tile[c16 + 15][sl]);
        u16* xp = &X[((size_t)(b * SEQ + st * 64 + sl)) * CDIM + ct * 64 + c16];
        *(uint4*)xp = o1;
        *(uint4*)(xp + 8) = o2;
    }
}

// ---------------- QKV projection GEMM (NT), 128x128 tiles, double-buffered async staging
// grid 18x12x2 = 432 blocks @ 2 blocks/CU (64KB LDS) -> fully resident, no tail round
__global__ __launch_bounds__(256, 2) void gemm_qkv_kernel(
        const u16* __restrict__ W, const u16* __restrict__ X,
        const float* __restrict__ bq, const float* __restrict__ bk, const float* __restrict__ bv,
        u16* __restrict__ Q, u16* __restrict__ K, u16* __restrict__ V) {
    __shared__ __align__(16) u16 sm[2 * (128 * 64 + 128 * 64)];   // 64 KB: [buf][As|Bs]
    const int n0 = blockIdx.x * 128;
    const int m0 = blockIdx.y * 128;
    const int b  = blockIdx.z;
    const int t = threadIdx.x;
    const int lane = t & 63, w = t >> 6;
    const int l16 = lane & 15, quad = lane >> 4;
    const int x7 = l16 & 7;
    const int srow = t >> 3, scol = (t & 7) * 8;
    const int scol_sw = ((t & 7) ^ (srow & 7)) * 8;   // swizzled source chunk
    const u16* Xb = X + (size_t)b * SEQ * CDIM;

    f32x4 acc[8][2] = {};

    // preload kb=0 into buf 0
    {
        u16* As = sm; u16* Bs = sm + 8192;
#pragma unroll
        for (int it = 0; it < 4; ++it) {
            int r2 = it * 32 + srow;
            cp16(&W [(size_t)(m0 + r2) * 512 + scol_sw], &As[r2 * 64 + scol]);
            cp16(&Xb[(size_t)(n0 + r2) * 512 + scol_sw], &Bs[r2 * 64 + scol]);
        }
    }
    for (int kb = 0; kb < 512; kb += 64) {
        const int pb = (kb >> 6) & 1;
        const u16* As = sm + pb * 16384;
        const u16* Bs = As + 8192;
        __syncthreads();                               // buf pb ready (vmcnt drain)
        if (kb + 64 < 512) {                           // prefetch next into buf pb^1
            u16* An = sm + (pb ^ 1) * 16384;
            u16* Bn = An + 8192;
#pragma unroll
            for (int it = 0; it < 4; ++it) {
                int r2 = it * 32 + srow;
                cp16(&W [(size_t)(m0 + r2) * 512 + kb + 64 + scol_sw], &An[r2 * 64 + scol]);
                cp16(&Xb[(size_t)(n0 + r2) * 512 + kb + 64 + scol_sw], &Bn[r2 * 64 + scol]);
            }
        }
#pragma unroll
        for (int kk = 0; kk < 2; ++kk) {
            const int co = ((kk * 4 + quad) ^ x7) * 8;
            short8 af[8], bfr[2];
#pragma unroll
            for (int j = 0; j < 2; ++j)
                bfr[j] = *(const short8*)&Bs[(w * 32 + j * 16 + l16) * 64 + co];
#pragma unroll
            for (int i = 0; i < 8; ++i)
                af[i] = *(const short8*)&As[(i * 16 + l16) * 64 + co];
#pragma unroll
            for (int i = 0; i < 8; ++i)
#pragma unroll
                for (int j = 0; j < 2; ++j)
                    acc[i][j] = mfma16(af[i], bfr[j], acc[i][j]);
        }
    }

    __syncthreads();                                   // done reading staging bufs
    if (m0 < 1024) {
        // Q/K epilogue: LDS bounce [s=128][d=128] stride 136, then 16B coalesced stores
        const bool isQ = (m0 < 512);
        const float* bias = isQ ? bq : bk;
        const float sc = isQ ? QSCALE : 1.0f;
        const int mq = isQ ? m0 : m0 - 512;            // 128-aligned head-pair base
        u16* dst = isQ ? Q : K;
        u16* qb = sm;
#pragma unroll
        for (int j = 0; j < 2; ++j) {
            int sl = w * 32 + j * 16 + l16;
#pragma unroll
            for (int i = 0; i < 8; ++i) {
                int md = i * 16 + quad * 4;            // local d 0..127
                int mm = mq + md;
                uint2 val;
                val.x = pkbf((acc[i][j][0] + bias[mm + 0]) * sc, (acc[i][j][1] + bias[mm + 1]) * sc);
                val.y = pkbf((acc[i][j][2] + bias[mm + 2]) * sc, (acc[i][j][3] + bias[mm + 3]) * sc);
                *(uint2*)&qb[sl * 136 + md] = val;
            }
        }
        __syncthreads();
#pragma unroll
        for (int it = 0; it < 8; ++it) {
            int v = it * 256 + t;
            int row = v >> 4, c8 = (v & 15) * 8;       // 128B per head-row, 2 heads per LDS row
            int hh = mq + c8;
            *(uint4*)&dst[(((size_t)(b * 8 + (hh >> 6))) * SEQ + n0 + row) * 64 + (hh & 63)] =
                *(const uint4*)&qb[row * 136 + c8];
        }
    } else {
        // V epilogue: LDS bounce [d=128][s=128] stride 136, then 16B coalesced row stores
        u16* vb = sm;
        const int mv = m0 - 1024;
#pragma unroll
        for (int j = 0; j < 2; ++j) {
            int sl = w * 32 + j * 16 + l16;
#pragma unroll
            for (int i = 0; i < 8; ++i) {
                int mb = i * 16 + quad * 4;
#pragma unroll
                for (int r = 0; r < 4; ++r)
                    vb[(mb + r) * 136 + sl] = f2bf(acc[i][j][r] + bv[mv + mb + r]);
            }
        }
        __syncthreads();
#pragma unroll
        for (int it = 0; it < 8; ++it) {
            int v = it * 256 + t;
            int row = v >> 4, ch = (v & 15) * 8;       // 16 chunks of 8 u16 per 128-col row
            *(uint4*)&V[((size_t)(b * 512 + mv + row)) * SEQ + n0 + ch] =
                *(const uint4*)&vb[row * 136 + ch];
        }
    }
}

// ---------------- flash attention partial (split-K x4), 128-q blocks (2 groups), dbuf K/V
// grid 288x4 = 1152 blocks @ 5 blocks/CU (160KB LDS) -> all co-resident, 4.5 waves/SIMD
__global__ __launch_bounds__(256, 5) void attn_partial(
        const u16* __restrict__ Q,    // [16][2304][64] (pre-scaled by QSCALE)
        const u16* __restrict__ K,    // [16][2304][64]
        const u16* __restrict__ Vt,   // [B][512][2304]
        u16* __restrict__ Opart,      // [4*16][2304][64] chunk-normalized bf16
        float* __restrict__ Lpart) {  // [4*16][2304]
    __shared__ __align__(16) u16 sm[2 * 8192];      // 32 KB: [buf][Ks|Vs], each 64x64
    const int pair = blockIdx.x & 15, qt = blockIdx.x >> 4;   // qt 0..17 (128-q tiles)
    const int c = blockIdx.y;
    const int b = pair >> 3, h = pair & 7;
    const int t = threadIdx.x, lane = t & 63, w = t >> 6;
    const int l16 = lane & 15, quad = lane >> 4;
    const int x7 = l16 & 7;
    const int srow = t >> 3;
    const int scol = (t & 7) * 8;
    const int scol_sw = ((t & 7) ^ (srow & 7)) * 8;
    const int kinv0 = kperm_inv(srow), kinv1 = kperm_inv(32 + srow);
    const int cA = (quad ^ x7) * 8;        // swizzled chunk for logical chunk quad
    const int cB = (quad ^ x7 ^ 4) * 8;    // swizzled chunk for logical chunk quad+4

    // Q fragments for two q-groups (B-frag: n=q, k=d)
    const u16* Qg = Q + ((size_t)pair * SEQ + qt * 128) * 64;
    const int rA = w * 16 + l16;
    short8 qf[2][2];
#pragma unroll
    for (int G = 0; G < 2; ++G) {
        qf[G][0] = *(const short8*)&Qg[(size_t)(G * 64 + rA) * 64 + quad * 8];
        qf[G][1] = *(const short8*)&Qg[(size_t)(G * 64 + rA) * 64 + 32 + quad * 8];
    }

    const u16* Kg = K  + ((size_t)pair * SEQ + c * 576) * 64;
    const u16* Vg = Vt + ((size_t)(b * 512 + h * 64)) * SEQ + c * 576;

    float lacc[2] = {0.f, 0.f};
    f32x4 o[2][4] = {};

    // preload kt=0 into buf 0
    {
        u16* Ks = sm; u16* Vs = sm + 4096;
        cp16(&Kg[(size_t)kinv0 * 64 + scol_sw], &Ks[srow * 64 + scol]);
        cp16(&Kg[(size_t)kinv1 * 64 + scol_sw], &Ks[(32 + srow) * 64 + scol]);
        cp16(&Vg[(size_t)srow * SEQ + scol_sw],        &Vs[srow * 64 + scol]);
        cp16(&Vg[(size_t)(32 + srow) * SEQ + scol_sw], &Vs[(32 + srow) * 64 + scol]);
    }
    for (int kt = 0; kt < 9; ++kt) {
        const int pb = kt & 1;
        const u16* Ks = sm + pb * 8192;
        const u16* Vs = Ks + 4096;
        __syncthreads();                              // buf pb ready
        if (kt < 8) {                                 // prefetch kt+1 into buf pb^1
            u16* Kn = sm + (pb ^ 1) * 8192;
            u16* Vn = Kn + 4096;
            cp16(&Kg[(size_t)((kt + 1) * 64 + kinv0) * 64 + scol_sw], &Kn[srow * 64 + scol]);
            cp16(&Kg[(size_t)((kt + 1) * 64 + kinv1) * 64 + scol_sw], &Kn[(32 + srow) * 64 + scol]);
            cp16(&Vg[(size_t)srow * SEQ + (kt + 1) * 64 + scol_sw],        &Vn[srow * 64 + scol]);
            cp16(&Vg[(size_t)(32 + srow) * SEQ + (kt + 1) * 64 + scol_sw], &Vn[(32 + srow) * 64 + scol]);
        }
        // S^T = K Q^T : rows = ki (kperm'd), cols = q; each kf read feeds 2 MFMAs
        f32x4 sacc[2][4];
        __builtin_amdgcn_s_setprio(1);
#pragma unroll
        for (int j = 0; j < 4; ++j) {
            short8 kf0 = *(const short8*)&Ks[(j * 16 + l16) * 64 + cA];
            short8 kf1 = *(const short8*)&Ks[(j * 16 + l16) * 64 + cB];
#pragma unroll
            for (int G = 0; G < 2; ++G) {
                f32x4 z = {0.f, 0.f, 0.f, 0.f};
                z = mfma16(kf0, qf[G][0], z);
                sacc[G][j] = mfma16(kf1, qf[G][1], z);
            }
        }
        __builtin_amdgcn_s_setprio(0);
        // fixed-max softmax; pack P (v_cvt_pk_bf16_f32) straight into PV B-fragments
        short8 pks[2][2];
#pragma unroll
        for (int G = 0; G < 2; ++G)
#pragma unroll
            for (int j = 0; j < 4; ++j) {
                float e0 = __builtin_amdgcn_exp2f(sacc[G][j][0]);
                float e1 = __builtin_amdgcn_exp2f(sacc[G][j][1]);
                float e2 = __builtin_amdgcn_exp2f(sacc[G][j][2]);
                float e3 = __builtin_amdgcn_exp2f(sacc[G][j][3]);
                lacc[G] += (e0 + e1) + (e2 + e3);
                u32* pw = (u32*)&pks[G][j >> 1];
                pw[(j & 1) * 2 + 0] = cvtpk(e0, e1);
                pw[(j & 1) * 2 + 1] = cvtpk(e2, e3);
            }
        // PV: P already in B-frag order thanks to kperm; each vf read feeds 2 MFMAs
        __builtin_amdgcn_s_setprio(1);
#pragma unroll
        for (int g = 0; g < 2; ++g) {
            const int cg = g ? cB : cA;
#pragma unroll
            for (int i = 0; i < 4; ++i) {
                short8 vf = *(const short8*)&Vs[(i * 16 + l16) * 64 + cg];
#pragma unroll
                for (int G = 0; G < 2; ++G)
                    o[G][i] = mfma16(vf, pks[G][g], o[G][i]);
            }
        }
        __builtin_amdgcn_s_setprio(0);
    }
    // reduce l across quads (lane's q = l16 within group)
    float linv[2];
#pragma unroll
    for (int G = 0; G < 2; ++G) {
        float lr = lacc[G];
        lr += __shfl_xor(lr, 16);
        lr += __shfl_xor(lr, 32);
        if (quad == 0) Lpart[((size_t)(c * 16 + pair)) * SEQ + qt * 128 + G * 64 + rA] = lr;
        linv[G] = 1.0f / lr;
    }
    const size_t orow = ((size_t)(c * 16 + pair)) * SEQ + qt * 128;

    // single merged bounce: 128 rows x 72 stride in the (now free) dbuf LDS
    __syncthreads();
#pragma unroll
    for (int G = 0; G < 2; ++G)
#pragma unroll
        for (int i = 0; i < 4; ++i) {
            uint2 pkv;
            pkv.x = cvtpk(o[G][i][0] * linv[G], o[G][i][1] * linv[G]);
            pkv.y = cvtpk(o[G][i][2] * linv[G], o[G][i][3] * linv[G]);
            *(uint2*)&sm[(G * 64 + rA) * 72 + i * 16 + quad * 4] = pkv;
        }
    __syncthreads();
#pragma unroll
    for (int it = 0; it < 4; ++it) {
        int v = it * 256 + t;
        int row = v >> 3, col = (v & 7) * 8;
        *(uint4*)&Opart[(orow + row) * 64 + col] = *(const uint4*)&sm[row * 72 + col];
    }
}

// ---------------- combine split-K partials -> At [B][2304][512] bf16 (16B/thread/chunk)
__global__ __launch_bounds__(256) void attn_combine(
        const u16* __restrict__ Opart, const float* __restrict__ Lpart,
        u16* __restrict__ At) {
    const int bid = blockIdx.x;
    const int pair = bid / 72, sb = bid % 72;
    const int t = threadIdx.x;
    const int rl = t >> 3, dg = t & 7;
    const int s = sb * 32 + rl;
    const int b = pair >> 3, h = pair & 7;
    float wc[NCHUNK], L = 0.f;
#pragma unroll
    for (int c = 0; c < NCHUNK; ++c) {
        wc[c] = Lpart[(size_t)(c * 16 + pair) * SEQ + s];
        L += wc[c];
    }
    float invL = 1.0f / L;
    float acc[8] = {};
#pragma unroll
    for (int c = 0; c < NCHUNK; ++c) {
        uint4 v = *(const uint4*)&Opart[((size_t)(c * 16 + pair) * SEQ + s) * 64 + dg * 8];
        const u16* pv = (const u16*)&v;
#pragma unroll
        for (int e = 0; e < 8; ++e)
            acc[e] += wc[c] * bf2f(pv[e]);
    }
    uint4 outv;
    outv.x = pkbf(acc[0] * invL, acc[1] * invL);
    outv.y = pkbf(acc[2] * invL, acc[3] * invL);
    outv.z = pkbf(acc[4] * invL, acc[5] * invL);
    outv.w = pkbf(acc[6] * invL, acc[7] * invL);
    *(uint4*)&At[((size_t)b * SEQ + s) * ND + h * 64 + dg * 8] = outv;
}

// ---------------- output projection GEMM (NT), 64x64 tiles, dbuf async staging
__global__ __launch_bounds__(256) void gemm_out_kernel(
        const u16* __restrict__ Wob, const u16* __restrict__ At,
        const float* __restrict__ bo, float* __restrict__ out) {
    __shared__ __align__(16) u16 sm[2 * 8192];       // 32 KB: [buf][As|Bs], each 64x64
    const int n0 = blockIdx.x * 64;
    const int m0 = blockIdx.y * 64;
    const int b  = blockIdx.z;
    const int t = threadIdx.x;
    const int lane = t & 63, w = t >> 6;
    const int l16 = lane & 15, quad = lane >> 4;
    const int x7 = l16 & 7;
    const int srow = t >> 3, scol = (t & 7) * 8;
    const int scol_sw = ((t & 7) ^ (srow & 7)) * 8;
    const u16* Ab = At + (size_t)b * SEQ * ND;

    f32x4 acc[4] = {};

    {
        u16* As = sm; u16* Bs = sm + 4096;
#pragma unroll
        for (int it = 0; it < 2; ++it) {
            int r2 = it * 32 + srow;
            cp16(&Wob[(size_t)(m0 + r2) * 512 + scol_sw], &As[r2 * 64 + scol]);
            cp16(&Ab [(size_t)(n0 + r2) * 512 + scol_sw], &Bs[r2 * 64 + scol]);
        }
    }
    for (int kb = 0; kb < 512; kb += 64) {
        const int pb = (kb >> 6) & 1;
        const u16* As = sm + pb * 8192;
        const u16* Bs = As + 4096;
        __syncthreads();
        if (kb + 64 < 512) {
            u16* An = sm + (pb ^ 1) * 8192;
            u16* Bn = An + 4096;
#pragma unroll
            for (int it = 0; it < 2; ++it) {
                int r2 = it * 32 + srow;
                cp16(&Wob[(size_t)(m0 + r2) * 512 + kb + 64 + scol_sw], &An[r2 * 64 + scol]);
                cp16(&Ab [(size_t)(n0 + r2) * 512 + kb + 64 + scol_sw], &Bn[r2 * 64 + scol]);
            }
        }
#pragma unroll
        for (int kk = 0; kk < 2; ++kk) {
            const int co = ((kk * 4 + quad) ^ x7) * 8;
            short8 af[4];
#pragma unroll
            for (int i = 0; i < 4; ++i)
                af[i] = *(const short8*)&As[(i * 16 + l16) * 64 + co];
            short8 bfr = *(const short8*)&Bs[(w * 16 + l16) * 64 + co];
#pragma unroll
            for (int i = 0; i < 4; ++i)
                acc[i] = mfma16(af[i], bfr, acc[i]);
        }
    }
    // epilogue: LDS bounce (64 c-rows x stride 68 f32 -> 2-way banks only),
    // then 4 coalesced float4 nontemporal stores/thread (256B bursts per c-row)
    __syncthreads();                                  // waves done reading staging bufs
    float* fb = (float*)sm;
#pragma unroll
    for (int i = 0; i < 4; ++i) {
        int cl = i * 16 + quad * 4;
        int s = w * 16 + l16;
#pragma unroll
        for (int r = 0; r < 4; ++r)
            fb[(cl + r) * 68 + s] = acc[i][r] + bo[m0 + cl + r];
    }
    __syncthreads();
#pragma unroll
    for (int k2 = 0; k2 < 4; ++k2) {
        int v = k2 * 256 + t;
        int row = v >> 4, c4 = (v & 15) * 4;
        f32x4 ov = *(const f32x4*)&fb[row * 68 + c4];
        __builtin_nontemporal_store(ov, (f32x4*)&out[((size_t)(b * 512 + m0 + row)) * SEQ + n0 + c4]);
    }
}

extern "C" void kernel_launch(void* const* d_in, const int* in_sizes, int n_in,
                              void* d_out, int out_size, void* d_ws, size_t ws_size,
                              hipStream_t stream) {
    const float* H  = (const float*)d_in[0];
    const float* Wq = (const float*)d_in[1];
    const float* bq = (const float*)d_in[2];
    const float* Wk = (const float*)d_in[3];
    const float* bk = (const float*)d_in[4];
    const float* Wv = (const float*)d_in[5];
    const float* bv = (const float*)d_in[6];
    const float* Wo = (const float*)d_in[7];
    const float* bo = (const float*)d_in[8];
    float* out = (float*)d_out;

    u16* ws    = (u16*)d_ws;
    u16* Wqkv  = ws;                                  // 1536*512
    u16* Wob   = Wqkv  + 1536 * 512;                  // 512*512
    u16* Xbf   = Wob   + 512 * 512;                   // 2*2304*512
    u16* Qb    = Xbf   + 2 * SEQ * CDIM;              // 16*2304*64
    u16* Kb    = Qb    + 2 * SEQ * ND;
    u16* Vb    = Kb    + 2 * SEQ * ND;
    u16* At    = Vb    + 2 * SEQ * ND;
    u16* Opart = At    + 2 * SEQ * ND;                // 64*2304*64
    float* Lpart = (float*)(Opart + NCHUNK * 16 * SEQ * 64);

    prep_kernel<<<1088, 256, 0, stream>>>(H, Wq, Wk, Wv, Wo, Wqkv, Wob, Xbf);
    gemm_qkv_kernel<<<dim3(18, 12, 2), 256, 0, stream>>>(Wqkv, Xbf, bq, bk, bv, Qb, Kb, Vb);
    attn_partial<<<dim3(288, NCHUNK), 256, 0, stream>>>(Qb, Kb, Vb, Opart, Lpart);
    attn_combine<<<1152, 256, 0, stream>>>(Opart, Lpart, At);
    gemm_out_kernel<<<dim3(36, 8, 2), 256, 0, stream>>>(Wob, At, bo, out);
}

// Round 8
// 126.184 us; speedup vs baseline: 1.4502x; 1.4502x over previous
//
#include <hip/hip_runtime.h>
#include <hip/hip_bf16.h>

#define HEADS 8
#define DHEAD 64
#define CDIM  512
#define SEQ   2304      // 48*48
#define ND    512       // HEADS*DHEAD
#define NCHUNK 4        // split-K chunks over the 36 key-tiles (9 tiles each)

typedef unsigned short u16;
typedef unsigned int   u32;
typedef __attribute__((ext_vector_type(8))) short short8;
typedef __attribute__((ext_vector_type(4))) float f32x4;
typedef __attribute__((ext_vector_type(4))) u32 u32x4;

#define QSCALE 0.18033688011112043f   // 0.125 * log2(e): folded into Q so softmax is exp2

__device__ __forceinline__ u16 f2bf(float f) {
    union { float f; u32 u; } x; x.f = f;
    u32 r = x.u + 0x7FFFu + ((x.u >> 16) & 1u);   // RNE
    return (u16)(r >> 16);
}
__device__ __forceinline__ float bf2f(u16 v) {
    union { u32 u; float f; } x; x.u = ((u32)v) << 16; return x.f;
}
// pack two f32 -> two bf16 in one u32 (round-half-up via +0x8000, then v_perm byte-select)
__device__ __forceinline__ u32 pkbf(float a, float b) {
    union { float f; u32 u; } x, y; x.f = a; y.f = b;
    return __builtin_amdgcn_perm(y.u + 0x8000u, x.u + 0x8000u, 0x07060302u);
}
// single-instruction packed f32->bf16 (RNE); lo result = first operand
__device__ __forceinline__ u32 cvtpk(float lo, float hi) {
    u32 r;
    asm("v_cvt_pk_bf16_f32 %0, %1, %2" : "=v"(r) : "v"(lo), "v"(hi));
    return r;
}
__device__ __forceinline__ f32x4 mfma16(short8 a, short8 b, f32x4 c) {
    return __builtin_amdgcn_mfma_f32_16x16x32_bf16(a, b, c, 0, 0, 0);
}
// async 16B global->LDS (wave-uniform base + lane*16 dest)
__device__ __forceinline__ void cp16(const void* g, void* l) {
    __builtin_amdgcn_global_load_lds(
        (const __attribute__((address_space(1))) u32*)(uintptr_t)g,
        (__attribute__((address_space(3))) u32*)(u32)(uintptr_t)l,
        16, 0, 0);
}
// LDS K-slot r holds source K row kperm_inv(r), so post-softmax P sits in PV B-frag order.
__device__ __forceinline__ int kperm_inv(int r) {
    return (r & ~0x1C) | ((r & 0x0C) << 1) | ((r & 0x10) >> 2);
}

// ---------------- fused: weight convert (uint4-vectorized) + x transpose (64x64 tiles)
__global__ void prep_kernel(const float* __restrict__ H,
                            const float* __restrict__ Wq, const float* __restrict__ Wk,
                            const float* __restrict__ Wv, const float* __restrict__ Wo,
                            u16* __restrict__ Wqkv, u16* __restrict__ Wob,
                            u16* __restrict__ X) {
    __shared__ float tile[64][65];
    const int t = threadIdx.x;
    const int bx = blockIdx.x;
    if (bx < 512) {
        const int N1 = CDIM * ND;                 // 262144 (divisible by 8)
        int i8 = (bx * 256 + t) * 8;
        const float* src;
        u16* dst;
        if (i8 < 3 * N1) {
            src = (i8 < N1) ? &Wq[i8] : (i8 < 2 * N1 ? &Wk[i8 - N1] : &Wv[i8 - 2 * N1]);
            dst = &Wqkv[i8];
        } else {
            src = &Wo[i8 - 3 * N1];
            dst = &Wob[i8 - 3 * N1];
        }
        float4 a = *(const float4*)src;
        float4 c = *(const float4*)(src + 4);
        uint4 o;
        o.x = pkbf(a.x, a.y); o.y = pkbf(a.z, a.w);
        o.z = pkbf(c.x, c.y); o.w = pkbf(c.z, c.w);
        *(uint4*)dst = o;
    } else {
        int bb = bx - 512;                        // 0..575
        int st = bb % 36, ct = (bb / 36) % 8, b = bb / (36 * 8);
        // load: 64 c-rows x 64 s, float4/thread x4 (coalesced along s)
#pragma unroll
        for (int it = 0; it < 4; ++it) {
            int cl = it * 16 + (t >> 4);
            int j4 = (t & 15) * 4;
            float4 hv = *(const float4*)&H[((size_t)(b * CDIM + ct * 64 + cl)) * SEQ + st * 64 + j4];
            tile[cl][j4 + 0] = hv.x; tile[cl][j4 + 1] = hv.y;
            tile[cl][j4 + 2] = hv.z; tile[cl][j4 + 3] = hv.w;
        }
        __syncthreads();
        // store: 64 s-rows, 16 consecutive c per thread as two uint4 (16 bf16 = 32B)
        int sl = t >> 2, c16 = (t & 3) * 16;
        uint4 o1, o2;
        o1.x = cvtpk(tile[c16 +  0][sl], tile[c16 +  1][sl]);
        o1.y = cvtpk(tile[c16 +  2][sl], tile[c16 +  3][sl]);
        o1.z = cvtpk(tile[c16 +  4][sl], tile[c16 +  5][sl]);
        o1.w = cvtpk(tile[c16 +  6][sl], tile[c16 +  7][sl]);
        o2.x = cvtpk(tile[c16 +  8][sl], tile[c16 +  9][sl]);
        o2.y = cvtpk(tile[c16 + 10][sl], tile[c16 + 11][sl]);
        o2.z = cvtpk(tile[c16 + 12][sl], tile[c16 + 13][sl]);
        o2.w = cvtpk(tile[c16 + 14][sl], tile[c16 + 15][sl]);
        u16* xp = &X[((size_t)(b * SEQ + st * 64 + sl)) * CDIM + ct * 64 + c16];
        *(uint4*)xp = o1;
        *(uint4*)(xp + 8) = o2;
    }
}

// ---------------- QKV projection GEMM (NT), 128x128 tiles, double-buffered async staging
// grid 18x12x2 = 432 blocks @ 2 blocks/CU (64KB LDS) -> fully resident, no tail round
__global__ __launch_bounds__(256, 2) void gemm_qkv_kernel(
        const u16* __restrict__ W, const u16* __restrict__ X,
        const float* __restrict__ bq, const float* __restrict__ bk, const float* __restrict__ bv,
        u16* __restrict__ Q, u16* __restrict__ K, u16* __restrict__ V) {
    __shared__ __align__(16) u16 sm[2 * (128 * 64 + 128 * 64)];   // 64 KB: [buf][As|Bs]
    const int n0 = blockIdx.x * 128;
    const int m0 = blockIdx.y * 128;
    const int b  = blockIdx.z;
    const int t = threadIdx.x;
    const int lane = t & 63, w = t >> 6;
    const int l16 = lane & 15, quad = lane >> 4;
    const int x7 = l16 & 7;
    const int srow = t >> 3, scol = (t & 7) * 8;
    const int scol_sw = ((t & 7) ^ (srow & 7)) * 8;   // swizzled source chunk
    const u16* Xb = X + (size_t)b * SEQ * CDIM;

    f32x4 acc[8][2] = {};

    // preload kb=0 into buf 0
    {
        u16* As = sm; u16* Bs = sm + 8192;
#pragma unroll
        for (int it = 0; it < 4; ++it) {
            int r2 = it * 32 + srow;
            cp16(&W [(size_t)(m0 + r2) * 512 + scol_sw], &As[r2 * 64 + scol]);
            cp16(&Xb[(size_t)(n0 + r2) * 512 + scol_sw], &Bs[r2 * 64 + scol]);
        }
    }
    for (int kb = 0; kb < 512; kb += 64) {
        const int pb = (kb >> 6) & 1;
        const u16* As = sm + pb * 16384;
        const u16* Bs = As + 8192;
        __syncthreads();                               // buf pb ready (vmcnt drain)
        if (kb + 64 < 512) {                           // prefetch next into buf pb^1
            u16* An = sm + (pb ^ 1) * 16384;
            u16* Bn = An + 8192;
#pragma unroll
            for (int it = 0; it < 4; ++it) {
                int r2 = it * 32 + srow;
                cp16(&W [(size_t)(m0 + r2) * 512 + kb + 64 + scol_sw], &An[r2 * 64 + scol]);
                cp16(&Xb[(size_t)(n0 + r2) * 512 + kb + 64 + scol_sw], &Bn[r2 * 64 + scol]);
            }
        }
#pragma unroll
        for (int kk = 0; kk < 2; ++kk) {
            const int co = ((kk * 4 + quad) ^ x7) * 8;
            short8 af[8], bfr[2];
#pragma unroll
            for (int j = 0; j < 2; ++j)
                bfr[j] = *(const short8*)&Bs[(w * 32 + j * 16 + l16) * 64 + co];
#pragma unroll
            for (int i = 0; i < 8; ++i)
                af[i] = *(const short8*)&As[(i * 16 + l16) * 64 + co];
#pragma unroll
            for (int i = 0; i < 8; ++i)
#pragma unroll
                for (int j = 0; j < 2; ++j)
                    acc[i][j] = mfma16(af[i], bfr[j], acc[i][j]);
        }
    }

    __syncthreads();                                   // done reading staging bufs
    if (m0 < 1024) {
        // Q/K epilogue: LDS bounce [s=128][d=128] stride 136, then 16B coalesced stores
        const bool isQ = (m0 < 512);
        const float* bias = isQ ? bq : bk;
        const float sc = isQ ? QSCALE : 1.0f;
        const int mq = isQ ? m0 : m0 - 512;            // 128-aligned head-pair base
        u16* dst = isQ ? Q : K;
        u16* qb = sm;
#pragma unroll
        for (int j = 0; j < 2; ++j) {
            int sl = w * 32 + j * 16 + l16;
#pragma unroll
            for (int i = 0; i < 8; ++i) {
                int md = i * 16 + quad * 4;            // local d 0..127
                int mm = mq + md;
                uint2 val;
                val.x = pkbf((acc[i][j][0] + bias[mm + 0]) * sc, (acc[i][j][1] + bias[mm + 1]) * sc);
                val.y = pkbf((acc[i][j][2] + bias[mm + 2]) * sc, (acc[i][j][3] + bias[mm + 3]) * sc);
                *(uint2*)&qb[sl * 136 + md] = val;
            }
        }
        __syncthreads();
#pragma unroll
        for (int it = 0; it < 8; ++it) {
            int v = it * 256 + t;
            int row = v >> 4, c8 = (v & 15) * 8;       // 128B per head-row, 2 heads per LDS row
            int hh = mq + c8;
            *(uint4*)&dst[(((size_t)(b * 8 + (hh >> 6))) * SEQ + n0 + row) * 64 + (hh & 63)] =
                *(const uint4*)&qb[row * 136 + c8];
        }
    } else {
        // V epilogue: LDS bounce [d=128][s=128] stride 136, then 16B coalesced row stores
        u16* vb = sm;
        const int mv = m0 - 1024;
#pragma unroll
        for (int j = 0; j < 2; ++j) {
            int sl = w * 32 + j * 16 + l16;
#pragma unroll
            for (int i = 0; i < 8; ++i) {
                int mb = i * 16 + quad * 4;
#pragma unroll
                for (int r = 0; r < 4; ++r)
                    vb[(mb + r) * 136 + sl] = f2bf(acc[i][j][r] + bv[mv + mb + r]);
            }
        }
        __syncthreads();
#pragma unroll
        for (int it = 0; it < 8; ++it) {
            int v = it * 256 + t;
            int row = v >> 4, ch = (v & 15) * 8;       // 16 chunks of 8 u16 per 128-col row
            *(uint4*)&V[((size_t)(b * 512 + mv + row)) * SEQ + n0 + ch] =
                *(const uint4*)&vb[row * 136 + ch];
        }
    }
}

// ---------------- flash attention partial (split-K x4), 192-q blocks (3 groups), dbuf K/V
// grid 192x4 = 768 blocks @ 3 blocks/CU -> exactly resident, VGPR 84 (no spill)
__global__ __launch_bounds__(256, 3) void attn_partial(
        const u16* __restrict__ Q,    // [16][2304][64] (pre-scaled by QSCALE)
        const u16* __restrict__ K,    // [16][2304][64]
        const u16* __restrict__ Vt,   // [B][512][2304]
        u16* __restrict__ Opart,      // [4*16][2304][64] chunk-normalized bf16
        float* __restrict__ Lpart) {  // [4*16][2304]
    __shared__ __align__(16) u16 sm[2 * 8192];      // 32 KB: [buf][Ks|Vs], each 64x64
    const int pair = blockIdx.x & 15, qt = blockIdx.x >> 4;   // qt 0..11 (192-q tiles)
    const int c = blockIdx.y;
    const int b = pair >> 3, h = pair & 7;
    const int t = threadIdx.x, lane = t & 63, w = t >> 6;
    const int l16 = lane & 15, quad = lane >> 4;
    const int x7 = l16 & 7;
    const int srow = t >> 3;
    const int scol = (t & 7) * 8;
    const int scol_sw = ((t & 7) ^ (srow & 7)) * 8;
    const int kinv0 = kperm_inv(srow), kinv1 = kperm_inv(32 + srow);
    const int cA = (quad ^ x7) * 8;        // swizzled chunk for logical chunk quad
    const int cB = (quad ^ x7 ^ 4) * 8;    // swizzled chunk for logical chunk quad+4

    // Q fragments for three q-groups (B-frag: n=q, k=d)
    const u16* Qg = Q + ((size_t)pair * SEQ + qt * 192) * 64;
    const int rA = w * 16 + l16;
    short8 qf[3][2];
#pragma unroll
    for (int G = 0; G < 3; ++G) {
        qf[G][0] = *(const short8*)&Qg[(size_t)(G * 64 + rA) * 64 + quad * 8];
        qf[G][1] = *(const short8*)&Qg[(size_t)(G * 64 + rA) * 64 + 32 + quad * 8];
    }

    const u16* Kg = K  + ((size_t)pair * SEQ + c * 576) * 64;
    const u16* Vg = Vt + ((size_t)(b * 512 + h * 64)) * SEQ + c * 576;

    float lacc[3] = {0.f, 0.f, 0.f};
    f32x4 o[3][4] = {};

    // preload kt=0 into buf 0
    {
        u16* Ks = sm; u16* Vs = sm + 4096;
        cp16(&Kg[(size_t)kinv0 * 64 + scol_sw], &Ks[srow * 64 + scol]);
        cp16(&Kg[(size_t)kinv1 * 64 + scol_sw], &Ks[(32 + srow) * 64 + scol]);
        cp16(&Vg[(size_t)srow * SEQ + scol_sw],        &Vs[srow * 64 + scol]);
        cp16(&Vg[(size_t)(32 + srow) * SEQ + scol_sw], &Vs[(32 + srow) * 64 + scol]);
    }
    for (int kt = 0; kt < 9; ++kt) {
        const int pb = kt & 1;
        const u16* Ks = sm + pb * 8192;
        const u16* Vs = Ks + 4096;
        __syncthreads();                              // buf pb ready
        if (kt < 8) {                                 // prefetch kt+1 into buf pb^1
            u16* Kn = sm + (pb ^ 1) * 8192;
            u16* Vn = Kn + 4096;
            cp16(&Kg[(size_t)((kt + 1) * 64 + kinv0) * 64 + scol_sw], &Kn[srow * 64 + scol]);
            cp16(&Kg[(size_t)((kt + 1) * 64 + kinv1) * 64 + scol_sw], &Kn[(32 + srow) * 64 + scol]);
            cp16(&Vg[(size_t)srow * SEQ + (kt + 1) * 64 + scol_sw],        &Vn[srow * 64 + scol]);
            cp16(&Vg[(size_t)(32 + srow) * SEQ + (kt + 1) * 64 + scol_sw], &Vn[(32 + srow) * 64 + scol]);
        }
        // S^T = K Q^T : rows = ki (kperm'd), cols = q; each kf read feeds 3 MFMAs
        f32x4 sacc[3][4];
        __builtin_amdgcn_s_setprio(1);
#pragma unroll
        for (int j = 0; j < 4; ++j) {
            short8 kf0 = *(const short8*)&Ks[(j * 16 + l16) * 64 + cA];
            short8 kf1 = *(const short8*)&Ks[(j * 16 + l16) * 64 + cB];
#pragma unroll
            for (int G = 0; G < 3; ++G) {
                f32x4 z = {0.f, 0.f, 0.f, 0.f};
                z = mfma16(kf0, qf[G][0], z);
                sacc[G][j] = mfma16(kf1, qf[G][1], z);
            }
        }
        __builtin_amdgcn_s_setprio(0);
        // fixed-max softmax; pack P (v_cvt_pk_bf16_f32) straight into PV B-fragments
        short8 pks[3][2];
#pragma unroll
        for (int G = 0; G < 3; ++G)
#pragma unroll
            for (int j = 0; j < 4; ++j) {
                float e0 = __builtin_amdgcn_exp2f(sacc[G][j][0]);
                float e1 = __builtin_amdgcn_exp2f(sacc[G][j][1]);
                float e2 = __builtin_amdgcn_exp2f(sacc[G][j][2]);
                float e3 = __builtin_amdgcn_exp2f(sacc[G][j][3]);
                lacc[G] += (e0 + e1) + (e2 + e3);
                u32* pw = (u32*)&pks[G][j >> 1];
                pw[(j & 1) * 2 + 0] = cvtpk(e0, e1);
                pw[(j & 1) * 2 + 1] = cvtpk(e2, e3);
            }
        // PV: P already in B-frag order thanks to kperm; each vf read feeds 3 MFMAs
        __builtin_amdgcn_s_setprio(1);
#pragma unroll
        for (int g = 0; g < 2; ++g) {
            const int cg = g ? cB : cA;
#pragma unroll
            for (int i = 0; i < 4; ++i) {
                short8 vf = *(const short8*)&Vs[(i * 16 + l16) * 64 + cg];
#pragma unroll
                for (int G = 0; G < 3; ++G)
                    o[G][i] = mfma16(vf, pks[G][g], o[G][i]);
            }
        }
        __builtin_amdgcn_s_setprio(0);
    }
    // reduce l across quads (lane's q = l16 within group)
    float linv[3];
#pragma unroll
    for (int G = 0; G < 3; ++G) {
        float lr = lacc[G];
        lr += __shfl_xor(lr, 16);
        lr += __shfl_xor(lr, 32);
        if (quad == 0) Lpart[((size_t)(c * 16 + pair)) * SEQ + qt * 192 + G * 64 + rA] = lr;
        linv[G] = 1.0f / lr;
    }
    const size_t orow = ((size_t)(c * 16 + pair)) * SEQ + qt * 192;

    // single merged bounce: 192 rows x 72 stride in the (now free) dbuf LDS
    __syncthreads();
#pragma unroll
    for (int G = 0; G < 3; ++G)
#pragma unroll
        for (int i = 0; i < 4; ++i) {
            uint2 pkv;
            pkv.x = cvtpk(o[G][i][0] * linv[G], o[G][i][1] * linv[G]);
            pkv.y = cvtpk(o[G][i][2] * linv[G], o[G][i][3] * linv[G]);
            *(uint2*)&sm[(G * 64 + rA) * 72 + i * 16 + quad * 4] = pkv;
        }
    __syncthreads();
    // nontemporal: Opart is write-once stream consumed by a later kernel (cross-XCD);
    // keep it from evicting the resident K/V working set in this XCD's L2
#pragma unroll
    for (int it = 0; it < 6; ++it) {
        int v = it * 256 + t;
        int row = v >> 3, col = (v & 7) * 8;
        u32x4 ov = *(const u32x4*)&sm[row * 72 + col];
        __builtin_nontemporal_store(ov, (u32x4*)&Opart[(orow + row) * 64 + col]);
    }
}

// ---------------- combine split-K partials -> At [B][2304][512] bf16 (16B/thread/chunk)
__global__ __launch_bounds__(256) void attn_combine(
        const u16* __restrict__ Opart, const float* __restrict__ Lpart,
        u16* __restrict__ At) {
    const int bid = blockIdx.x;
    const int pair = bid / 72, sb = bid % 72;
    const int t = threadIdx.x;
    const int rl = t >> 3, dg = t & 7;
    const int s = sb * 32 + rl;
    const int b = pair >> 3, h = pair & 7;
    float wc[NCHUNK], L = 0.f;
#pragma unroll
    for (int c = 0; c < NCHUNK; ++c) {
        wc[c] = Lpart[(size_t)(c * 16 + pair) * SEQ + s];
        L += wc[c];
    }
    float invL = 1.0f / L;
    float acc[8] = {};
#pragma unroll
    for (int c = 0; c < NCHUNK; ++c) {
        uint4 v = *(const uint4*)&Opart[((size_t)(c * 16 + pair) * SEQ + s) * 64 + dg * 8];
        const u16* pv = (const u16*)&v;
#pragma unroll
        for (int e = 0; e < 8; ++e)
            acc[e] += wc[c] * bf2f(pv[e]);
    }
    uint4 outv;
    outv.x = pkbf(acc[0] * invL, acc[1] * invL);
    outv.y = pkbf(acc[2] * invL, acc[3] * invL);
    outv.z = pkbf(acc[4] * invL, acc[5] * invL);
    outv.w = pkbf(acc[6] * invL, acc[7] * invL);
    *(uint4*)&At[((size_t)b * SEQ + s) * ND + h * 64 + dg * 8] = outv;
}

// ---------------- output projection GEMM (NT), 64x64 tiles, dbuf async staging
__global__ __launch_bounds__(256) void gemm_out_kernel(
        const u16* __restrict__ Wob, const u16* __restrict__ At,
        const float* __restrict__ bo, float* __restrict__ out) {
    __shared__ __align__(16) u16 sm[2 * 8192];       // 32 KB: [buf][As|Bs], each 64x64
    const int n0 = blockIdx.x * 64;
    const int m0 = blockIdx.y * 64;
    const int b  = blockIdx.z;
    const int t = threadIdx.x;
    const int lane = t & 63, w = t >> 6;
    const int l16 = lane & 15, quad = lane >> 4;
    const int x7 = l16 & 7;
    const int srow = t >> 3, scol = (t & 7) * 8;
    const int scol_sw = ((t & 7) ^ (srow & 7)) * 8;
    const u16* Ab = At + (size_t)b * SEQ * ND;

    f32x4 acc[4] = {};

    {
        u16* As = sm; u16* Bs = sm + 4096;
#pragma unroll
        for (int it = 0; it < 2; ++it) {
            int r2 = it * 32 + srow;
            cp16(&Wob[(size_t)(m0 + r2) * 512 + scol_sw], &As[r2 * 64 + scol]);
            cp16(&Ab [(size_t)(n0 + r2) * 512 + scol_sw], &Bs[r2 * 64 + scol]);
        }
    }
    for (int kb = 0; kb < 512; kb += 64) {
        const int pb = (kb >> 6) & 1;
        const u16* As = sm + pb * 8192;
        const u16* Bs = As + 4096;
        __syncthreads();
        if (kb + 64 < 512) {
            u16* An = sm + (pb ^ 1) * 8192;
            u16* Bn = An + 4096;
#pragma unroll
            for (int it = 0; it < 2; ++it) {
                int r2 = it * 32 + srow;
                cp16(&Wob[(size_t)(m0 + r2) * 512 + kb + 64 + scol_sw], &An[r2 * 64 + scol]);
                cp16(&Ab [(size_t)(n0 + r2) * 512 + kb + 64 + scol_sw], &Bn[r2 * 64 + scol]);
            }
        }
#pragma unroll
        for (int kk = 0; kk < 2; ++kk) {
            const int co = ((kk * 4 + quad) ^ x7) * 8;
            short8 af[4];
#pragma unroll
            for (int i = 0; i < 4; ++i)
                af[i] = *(const short8*)&As[(i * 16 + l16) * 64 + co];
            short8 bfr = *(const short8*)&Bs[(w * 16 + l16) * 64 + co];
#pragma unroll
            for (int i = 0; i < 4; ++i)
                acc[i] = mfma16(af[i], bfr, acc[i]);
        }
    }
    // epilogue: LDS bounce (64 c-rows x stride 68 f32 -> 2-way banks only),
    // then 4 coalesced float4 nontemporal stores/thread (256B bursts per c-row)
    __syncthreads();                                  // waves done reading staging bufs
    float* fb = (float*)sm;
#pragma unroll
    for (int i = 0; i < 4; ++i) {
        int cl = i * 16 + quad * 4;
        int s = w * 16 + l16;
#pragma unroll
        for (int r = 0; r < 4; ++r)
            fb[(cl + r) * 68 + s] = acc[i][r] + bo[m0 + cl + r];
    }
    __syncthreads();
#pragma unroll
    for (int k2 = 0; k2 < 4; ++k2) {
        int v = k2 * 256 + t;
        int row = v >> 4, c4 = (v & 15) * 4;
        f32x4 ov = *(const f32x4*)&fb[row * 68 + c4];
        __builtin_nontemporal_store(ov, (f32x4*)&out[((size_t)(b * 512 + m0 + row)) * SEQ + n0 + c4]);
    }
}

extern "C" void kernel_launch(void* const* d_in, const int* in_sizes, int n_in,
                              void* d_out, int out_size, void* d_ws, size_t ws_size,
                              hipStream_t stream) {
    const float* H  = (const float*)d_in[0];
    const float* Wq = (const float*)d_in[1];
    const float* bq = (const float*)d_in[2];
    const float* Wk = (const float*)d_in[3];
    const float* bk = (const float*)d_in[4];
    const float* Wv = (const float*)d_in[5];
    const float* bv = (const float*)d_in[6];
    const float* Wo = (const float*)d_in[7];
    const float* bo = (const float*)d_in[8];
    float* out = (float*)d_out;

    u16* ws    = (u16*)d_ws;
    u16* Wqkv  = ws;                                  // 1536*512
    u16* Wob   = Wqkv  + 1536 * 512;                  // 512*512
    u16* Xbf   = Wob   + 512 * 512;                   // 2*2304*512
    u16* Qb    = Xbf   + 2 * SEQ * CDIM;              // 16*2304*64
    u16* Kb    = Qb    + 2 * SEQ * ND;
    u16* Vb    = Kb    + 2 * SEQ * ND;
    u16* At    = Vb    + 2 * SEQ * ND;
    u16* Opart = At    + 2 * SEQ * ND;                // 64*2304*64
    float* Lpart = (float*)(Opart + NCHUNK * 16 * SEQ * 64);

    prep_kernel<<<1088, 256, 0, stream>>>(H, Wq, Wk, Wv, Wo, Wqkv, Wob, Xbf);
    gemm_qkv_kernel<<<dim3(18, 12, 2), 256, 0, stream>>>(Wqkv, Xbf, bq, bk, bv, Qb, Kb, Vb);
    attn_partial<<<dim3(192, NCHUNK), 256, 0, stream>>>(Qb, Kb, Vb, Opart, Lpart);
    attn_combine<<<1152, 256, 0, stream>>>(Opart, Lpart, At);
    gemm_out_kernel<<<dim3(36, 8, 2), 256, 0, stream>>>(Wob, At, bo, out);
}